// Round 5
// baseline (94.460 us; speedup 1.0000x reference)
//
#include <hip/hip_runtime.h>
#include <math.h>

#define NB 64
#define Q 900
#define NC 81
#define NC2 80
#define HD 256
#define NV 117
#define NEGV -1000000000.0f

// ---------------- ws layout (bytes) ----------------
static const size_t OFF_TK = 0;        // 96 slots/img (i32/f32 views), 64*96*4 = 24576
static const size_t OFF_CM = 32768;    // f32 [64*30*256] summed C

typedef float float4u __attribute__((ext_vector_type(4), aligned(4)));

// ================= KA: fused softmax + per-class NMS + topk (1 block/image) ==========
__global__ __launch_bounds__(1024) void k_fused(const float* __restrict__ logits,
                                                const float* __restrict__ boxes,
                                                int* __restrict__ tki,
                                                float* __restrict__ tkf) {
#pragma clang fp contract(off)
  int img = blockIdx.x, t = threadIdx.x;
  int w = t >> 6, lane = t & 63;
  size_t imgQ = (size_t)img * Q;

  __shared__ float s_box[Q * 4];      // 14400 B
  __shared__ float s_sc[Q];           // 3600
  __shared__ int   s_lab[Q];          // 3600
  __shared__ float s_hsc[Q];          // 3600
  __shared__ float s_osc[Q];          // 3600
  __shared__ int   s_gidx[16][64];    // 4096
  __shared__ int   s_gsrt[16][64];    // 4096
  __shared__ float s_wmax[16];

  // ---- stage boxes + per-image box max ----
  const float4* bp4 = (const float4*)(boxes + imgQ * 4);
  float bm = -INFINITY;
  if (t < Q) {
    float4 v = bp4[t];
    ((float4*)s_box)[t] = v;
    bm = fmaxf(fmaxf(v.x, v.y), fmaxf(v.z, v.w));
  }
  #pragma unroll
  for (int s = 32; s > 0; s >>= 1) bm = fmaxf(bm, __shfl_xor(bm, s));
  if (lane == 0) s_wmax[w] = bm;

  // ---- softmax of row t (one row per thread) ----
  if (t < Q) {
    const float* lp = logits + (imgQ + t) * NC;
    float4u x[20];
    #pragma unroll
    for (int j = 0; j < 20; j++) x[j] = *(const float4u*)(lp + 4 * j);
    float x80 = lp[80];
    float m = x80;
    #pragma unroll
    for (int j = 0; j < 20; j++)
      m = fmaxf(m, fmaxf(fmaxf(x[j].x, x[j].y), fmaxf(x[j].z, x[j].w)));
    float e = 0.0f;
    #pragma unroll
    for (int j = 0; j < 20; j++)
      e += expf(x[j].x - m) + expf(x[j].y - m) + expf(x[j].z - m) + expf(x[j].w - m);
    e += expf(x80 - m);
    float bv = -INFINITY; int bi = 0;
    #pragma unroll
    for (int j = 0; j < 20; j++) {
      if (x[j].x > bv) { bv = x[j].x; bi = 4 * j; }
      if (x[j].y > bv) { bv = x[j].y; bi = 4 * j + 1; }
      if (x[j].z > bv) { bv = x[j].z; bi = 4 * j + 2; }
      if (x[j].w > bv) { bv = x[j].w; bi = 4 * j + 3; }
    }
    s_sc[t] = expf(bv - m) / e;
    s_lab[t] = bi;
    s_hsc[t] = NEGV;
    s_osc[t] = NEGV;
  }
  __syncthreads();

  float bmax = s_wmax[0];
  #pragma unroll
  for (int i = 1; i < 16; i++) bmax = fmaxf(bmax, s_wmax[i]);

  // ---- per-class greedy NMS: wave w handles classes w*5 .. w*5+4 ----
  unsigned long long lmask = (1ull << lane) - 1ull;
  for (int cc = 0; cc < 5; cc++) {
    int c = w * 5 + cc;
    // prefetch labels/scores from LDS, ballot-compact ascending-index
    int lb[15]; float sc[15];
    #pragma unroll
    for (int e = 0; e < 15; e++) {
      int i = e * 64 + lane;
      lb[e] = (i < Q) ? s_lab[i] : -1;
      sc[e] = (i < Q) ? s_sc[i] : 0.0f;
    }
    int n = 0;
    #pragma unroll
    for (int e = 0; e < 15; e++) {
      bool memb = (lb[e] == c);
      unsigned long long mm = __ballot(memb);
      if (memb) {
        int pos = n + __popcll(mm & lmask);
        if (pos < 64) s_gidx[w][pos] = e * 64 + lane;
      }
      n += __popcll(mm);
    }
    n = min(n, 64);
    int   myidx = (lane < n) ? s_gidx[w][lane] : 0;
    float mysc  = (lane < n) ? s_sc[myidx] : -INFINITY;

    // stable rank (score desc, index asc); gathered order is index-asc
    int rank = 0;
    for (int j = 0; j < n; j++) {
      float sj = __shfl(mysc, j);
      rank += (sj > mysc) || (sj == mysc && j < lane);
    }
    if (lane < n) s_gsrt[w][rank] = myidx;
    int oi = (lane < n) ? s_gsrt[w][lane] : 0;
    float os = (lane < n) ? s_sc[oi] : 0.0f;

    // offset box (per-element +off, matches reference rounding)
    float b0 = 0.f, b1 = 0.f, b2 = 0.f, b3 = 0.f;
    if (lane < n) {
      float off = (float)c * (bmax + 1.0f);
      b0 = s_box[oi * 4 + 0] + off; b1 = s_box[oi * 4 + 1] + off;
      b2 = s_box[oi * 4 + 2] + off; b3 = s_box[oi * 4 + 3] + off;
    }
    float areaA = (b2 - b0) * (b3 - b1);

    unsigned long long sup = 0;
    for (int j = 0; j < n; j++) {
      float c0 = __shfl(b0, j), c1 = __shfl(b1, j);
      float c2 = __shfl(b2, j), c3 = __shfl(b3, j);
      if (j > lane && lane < n) {
        float ltx = fmaxf(b0, c0), lty = fmaxf(b1, c1);
        float rbx = fminf(b2, c2), rby = fminf(b3, c3);
        float ww = fmaxf(rbx - ltx, 0.0f), hh = fmaxf(rby - lty, 0.0f);
        float inter = ww * hh;
        float areaB = (c2 - c0) * (c3 - c1);
        float uni = areaA + areaB - inter;
        float denom = (uni == 0.0f) ? 1.0f : uni;
        if (inter / denom > 0.5f) sup |= (1ull << j);
      }
    }

    unsigned long long keepm = (n >= 64) ? ~0ull : ((1ull << n) - 1ull);
    for (int i = 0; i < n; i++) {
      unsigned long long row = __shfl(sup, i);
      if ((keepm >> i) & 1ull) keepm &= ~row;
    }

    if (lane < n) {
      int kept = (int)((keepm >> lane) & 1ull);
      float val = kept ? os : NEGV;
      if (c == 0) s_hsc[oi] = val;
      else        s_osc[oi] = val;
    }
  }
  __syncthreads();

  // ---- topk: wave0 = humans, wave1 = objects ----
  if (w < 2) {
    const float* src = (w == 0) ? s_hsc : s_osc;
    float v[15];
    int cnt = 0;
    #pragma unroll
    for (int e = 0; e < 15; e++) {
      int i = e * 64 + lane;
      float val = (i < Q) ? src[i] : -INFINITY;
      cnt += (val >= 0.2f) ? 1 : 0;
      v[e] = val;
    }
    #pragma unroll
    for (int s = 32; s > 0; s >>= 1) cnt += __shfl_xor(cnt, s);

    float selv = 0.f; int seli = 0;
    for (int r = 0; r < 15; r++) {
      float bv_ = -INFINITY; int bi_ = 0x7fffffff;
      #pragma unroll
      for (int e = 0; e < 15; e++) { if (v[e] > bv_) { bv_ = v[e]; bi_ = e * 64 + lane; } }
      #pragma unroll
      for (int s = 32; s > 0; s >>= 1) {
        float ov = __shfl_xor(bv_, s); int oi2 = __shfl_xor(bi_, s);
        if (ov > bv_ || (ov == bv_ && oi2 < bi_)) { bv_ = ov; bi_ = oi2; }
      }
      if (lane == r) { selv = bv_; seli = bi_; }
      if ((bi_ & 63) == lane) {
        int ee = bi_ >> 6;
        #pragma unroll
        for (int e = 0; e < 15; e++) if (e == ee) v[e] = -2.0e9f;
      }
    }
    int kk = min(max(cnt, 3), 15);
    if (lane < 15) {
      tki[img * 96 + w * 15 + lane]      = seli;
      tkf[img * 96 + 30 + w * 15 + lane] = selv;
      tki[img * 96 + 60 + w * 15 + lane] = (lane < kk && selv > -5.0e8f) ? 1 : 0;
    }
  }
}

// ================= KB: GEMM, grid (4 n-slices, 64 images), full K ==========
__global__ __launch_bounds__(256) void k_gemm2(const float* __restrict__ hs,
                                               const int* __restrict__ tki,
                                               const float* __restrict__ Wv,
                                               const float* __restrict__ Wb,
                                               float* __restrict__ Cm) {
  int ns = blockIdx.x, img = blockIdx.y, t = threadIdx.x;
  __shared__ float s_At[256][40];   // A transposed [k][row], row pitch 160B (16B-aligned)
  __shared__ float s_B[32][64];
  __shared__ int s_row[30];
  if (t < 30) s_row[t] = tki[img * 96 + t];
  __syncthreads();
  // stage A transposed: f = q*30 + r  (lanes hit distinct rows -> conflict-free LDS writes)
  for (int f = t; f < 1920; f += 256) {
    int r = f % 30, q = f / 30;     // q = float4 chunk 0..63
    float4 a = *(const float4*)(hs + ((size_t)img * Q + s_row[r]) * HD + q * 4);
    s_At[q * 4 + 0][r] = a.x;
    s_At[q * 4 + 1][r] = a.y;
    s_At[q * 4 + 2][r] = a.z;
    s_At[q * 4 + 3][r] = a.w;
  }
  // per-thread B column source (branch hoisted)
  int col = ns * 64 + (t & 63);
  const float* Wsrc = nullptr; int roff = 0, kadd = 0, wstride = 0;
  if (col < 117)      { Wsrc = Wv; roff = col;       kadd = 0;   wstride = 117; }
  else if (col < 125) { Wsrc = Wb; roff = col - 117; kadd = 0;   wstride = 8; }
  else if (col < 242) { Wsrc = Wv; roff = col - 125; kadd = 256; wstride = 117; }
  else if (col < 250) { Wsrc = Wb; roff = col - 242; kadd = 256; wstride = 8; }

  int a = t >> 6;                   // row group: rows 8a..8a+7
  float acc[8] = {0, 0, 0, 0, 0, 0, 0, 0};
  __syncthreads();
  for (int kc = 0; kc < 256; kc += 32) {
    #pragma unroll
    for (int pp = 0; pp < 8; pp++) {
      int k_l = (t >> 6) + pp * 4;
      s_B[k_l][t & 63] = Wsrc ? Wsrc[(size_t)(kc + k_l + kadd) * wstride + roff] : 0.0f;
    }
    __syncthreads();
    #pragma unroll
    for (int kk = 0; kk < 32; kk++) {
      float4 a0 = *(const float4*)(&s_At[kc + kk][8 * a]);       // broadcast reads
      float4 a1 = *(const float4*)(&s_At[kc + kk][8 * a + 4]);
      float b = s_B[kk][t & 63];
      acc[0] += a0.x * b; acc[1] += a0.y * b; acc[2] += a0.z * b; acc[3] += a0.w * b;
      acc[4] += a1.x * b; acc[5] += a1.y * b; acc[6] += a1.z * b; acc[7] += a1.w * b;
    }
    __syncthreads();
  }
  #pragma unroll
  for (int j = 0; j < 8; j++) {
    int r = 8 * a + j;
    if (r < 30) Cm[((size_t)img * 30 + r) * 256 + col] = acc[j];
  }
}

// ================= KC: epilogue, all four outputs ==========
__global__ __launch_bounds__(512) void k_out2(const float* __restrict__ boxes,
                                              const float* __restrict__ sizes,
                                              const float* __restrict__ Cm,
                                              const int* __restrict__ tki,
                                              const float* __restrict__ tkf,
                                              const float* __restrict__ bverb,
                                              const float* __restrict__ bbox,
                                              float* __restrict__ out) {
  int img = blockIdx.x, t = threadIdx.x;
  __shared__ float s_C[30 * 256];
  __shared__ float s_pr[225];
  __shared__ int s_ih[15], s_io[15];
  const float4* base = (const float4*)(Cm + (size_t)img * 7680);
  for (int e = t; e < 1920; e += 512) ((float4*)s_C)[e] = base[e];
  if (t < 15) { s_ih[t] = tki[img * 96 + t]; s_io[t] = tki[img * 96 + 15 + t]; }
  if (t < 225) {
    int h_ = t / 15, o_ = t - h_ * 15;
    float th = tkf[img * 96 + 30 + h_], to_ = tkf[img * 96 + 45 + o_];
    int vh = tki[img * 96 + 60 + h_], vo = tki[img * 96 + 75 + o_];
    s_pr[t] = (vh && vo) ? th * to_ : 0.0f;
  }
  __syncthreads();

  float hgt = sizes[img * 2 + 0], wid = sizes[img * 2 + 1];
  float* out0 = out;
  float* out1 = out + 7680;
  float* out2 = out + 65280;
  float* out3 = out + 122880;

  if (t < 30) {
    int q = (t < 15) ? s_ih[t] : s_io[t - 15];
    const float* bp = boxes + ((size_t)img * Q + q) * 4;
    float cx = bp[0], cy = bp[1], w = bp[2], h = bp[3];
    float* o = out0 + ((size_t)img * 30 + t) * 4;
    o[0] = (cx - 0.5f * w) * wid;
    o[1] = (cy - 0.5f * h) * hgt;
    o[2] = (cx + 0.5f * w) * wid;
    o[3] = (cy + 0.5f * h) * hgt;
  }

  if (t < 225) {
    int h_ = t / 15, o_ = t - h_ * 15;
    {
      float d0 = s_C[h_ * 256 + 117] + s_C[(15 + o_) * 256 + 242] + bbox[0];
      float d1 = s_C[h_ * 256 + 118] + s_C[(15 + o_) * 256 + 243] + bbox[1];
      float d2 = s_C[h_ * 256 + 119] + s_C[(15 + o_) * 256 + 244] + bbox[2];
      float d3 = s_C[h_ * 256 + 120] + s_C[(15 + o_) * 256 + 245] + bbox[3];
      int q = s_ih[h_];
      const float* bp = boxes + ((size_t)img * Q + q) * 4;
      float cx = bp[0], cy = bp[1], w = bp[2], h = bp[3];
      float cx2 = cx + d0 * w, cy2 = cy + d1 * h;
      float w2 = w * expf(d2), h2 = h * expf(d3);
      float* o = out1 + ((size_t)img * 225 + t) * 4;
      o[0] = (cx2 - 0.5f * w2) * wid;
      o[1] = (cy2 - 0.5f * h2) * hgt;
      o[2] = (cx2 + 0.5f * w2) * wid;
      o[3] = (cy2 + 0.5f * h2) * hgt;
    }
    {
      float d4 = s_C[h_ * 256 + 121] + s_C[(15 + o_) * 256 + 246] + bbox[4];
      float d5 = s_C[h_ * 256 + 122] + s_C[(15 + o_) * 256 + 247] + bbox[5];
      float d6 = s_C[h_ * 256 + 123] + s_C[(15 + o_) * 256 + 248] + bbox[6];
      float d7 = s_C[h_ * 256 + 124] + s_C[(15 + o_) * 256 + 249] + bbox[7];
      int q = s_io[o_];
      const float* bp = boxes + ((size_t)img * Q + q) * 4;
      float cx = bp[0], cy = bp[1], w = bp[2], h = bp[3];
      float cx2 = cx + d4 * w, cy2 = cy + d5 * h;
      float w2 = w * expf(d6), h2 = h * expf(d7);
      float* o = out2 + ((size_t)img * 225 + t) * 4;
      o[0] = (cx2 - 0.5f * w2) * wid;
      o[1] = (cy2 - 0.5f * h2) * hgt;
      o[2] = (cx2 + 0.5f * w2) * wid;
      o[3] = (cy2 + 0.5f * h2) * hgt;
    }
  }

  for (int e = t; e < 225 * 117; e += 512) {
    int p = e / 117, v = e - p * 117;
    int ph = p / 15, po = p - ph * 15;
    float x = s_C[ph * 256 + v] + s_C[(15 + po) * 256 + 125 + v] + bverb[v];
    out3[(size_t)img * 26325 + e] = (1.0f / (1.0f + expf(-x))) * s_pr[p];
  }
}

extern "C" void kernel_launch(void* const* d_in, const int* in_sizes, int n_in,
                              void* d_out, int out_size, void* d_ws, size_t ws_size,
                              hipStream_t stream) {
  const float* logits = (const float*)d_in[0];
  const float* boxes  = (const float*)d_in[1];
  const float* hs     = (const float*)d_in[2];
  const float* sizes  = (const float*)d_in[3];
  const float* Wv     = (const float*)d_in[4];
  const float* bv     = (const float*)d_in[5];
  const float* Wb     = (const float*)d_in[6];
  const float* bb     = (const float*)d_in[7];
  float* out = (float*)d_out;
  char* ws = (char*)d_ws;

  int*   tki = (int*)(ws + OFF_TK);
  float* tkf = (float*)(ws + OFF_TK);
  float* Cm  = (float*)(ws + OFF_CM);

  k_fused<<<NB, 1024, 0, stream>>>(logits, boxes, tki, tkf);
  k_gemm2<<<dim3(4, NB), 256, 0, stream>>>(hs, tki, Wv, Wb, Cm);
  k_out2<<<NB, 512, 0, stream>>>(boxes, sizes, Cm, tki, tkf, bv, bb, out);
}

// Round 6
// 68.874 us; speedup vs baseline: 1.3715x; 1.3715x over previous
//
#include <hip/hip_runtime.h>
#include <math.h>

#define NB 64
#define Q 900
#define NC 81
#define NC2 80
#define HD 256
#define NV 117
#define NEGV -1000000000.0f

// ---------------- ws layout (bytes) ----------------
static const size_t OFF_SCORES = 0;          // f32 [NB*Q]
static const size_t OFF_LABELS = 230400;     // i32 [NB*Q]
static const size_t OFF_HSC    = 460800;     // f32 [NB*Q] masked human scores
static const size_t OFF_OSC    = 691200;     // f32 [NB*Q] masked object scores
static const size_t OFF_TK     = 921600;     // 96 slots/img (i32/f32 views)
static const size_t OFF_CM     = 1048576;    // f32 [64*30*256] summed C

typedef float float4u __attribute__((ext_vector_type(4), aligned(4)));

// ---------------- scores / labels: 4-lane quad per row, float4 loads ----------------
__global__ __launch_bounds__(256) void k_score(const float* __restrict__ logits,
                                               float* __restrict__ scores,
                                               int* __restrict__ labels) {
  int quad = threadIdx.x >> 2, qq = threadIdx.x & 3;
  int row = blockIdx.x * 64 + quad;          // grid = 900 -> 57600 rows exactly
  const float* lp = logits + (size_t)row * NC;
  float4u x[5];
  #pragma unroll
  for (int j = 0; j < 5; j++) {
    int c = qq + 4 * j;                      // chunk 0..19, covers idx 0..79
    x[j] = *(const float4u*)(lp + c * 4);
  }
  float x80 = (qq == 0) ? lp[80] : -INFINITY;
  float m = x80;
  #pragma unroll
  for (int j = 0; j < 5; j++)
    m = fmaxf(m, fmaxf(fmaxf(x[j].x, x[j].y), fmaxf(x[j].z, x[j].w)));
  m = fmaxf(m, __shfl_xor(m, 1));
  m = fmaxf(m, __shfl_xor(m, 2));
  float e = (qq == 0) ? expf(x80 - m) : 0.0f;
  #pragma unroll
  for (int j = 0; j < 5; j++)
    e += expf(x[j].x - m) + expf(x[j].y - m) + expf(x[j].z - m) + expf(x[j].w - m);
  e += __shfl_xor(e, 1);
  e += __shfl_xor(e, 2);
  // argmax over idx 0..79, lowest index wins ties (strict > keeps lowest in-lane)
  float bv = -INFINITY; int bi = 0x7fffffff;
  #pragma unroll
  for (int j = 0; j < 5; j++) {
    int base = (qq + 4 * j) * 4;
    if (x[j].x > bv) { bv = x[j].x; bi = base; }
    if (x[j].y > bv) { bv = x[j].y; bi = base + 1; }
    if (x[j].z > bv) { bv = x[j].z; bi = base + 2; }
    if (x[j].w > bv) { bv = x[j].w; bi = base + 3; }
  }
  #pragma unroll
  for (int s = 1; s <= 2; s <<= 1) {
    float ov = __shfl_xor(bv, s); int oi = __shfl_xor(bi, s);
    if (ov > bv || (ov == bv && oi < bi)) { bv = ov; bi = oi; }
  }
  if (qq == 0) {
    scores[row] = expf(bv - m) / e;
    labels[row] = bi;
  }
}

// ---------------- per-(image,class) greedy NMS -> masked score arrays ----------------
// Suppression is exactly block-diagonal per class (offset separation), so global
// greedy NMS == independent per-class greedy NMS. One wave per (img,class).
__global__ __launch_bounds__(256) void k_cnms(const float* __restrict__ scores,
                                              const int* __restrict__ labels,
                                              const float* __restrict__ boxes,
                                              float* __restrict__ hsc,
                                              float* __restrict__ osc) {
#pragma clang fp contract(off)
  int img = blockIdx.x;
  int tid = threadIdx.x;
  int wid = tid >> 6, lane = tid & 63;
  int c = blockIdx.y * 4 + wid;
  size_t imgQ = (size_t)img * Q;
  __shared__ int   s_idx[4][64];
  __shared__ float s_sc[4][64];
  __shared__ int   s_srt[4][64];
  __shared__ float s_ssc[4][64];
  __shared__ float s_wmax[4];

  // per-image box max (order-independent, bit-exact)
  const float4* bp4 = (const float4*)(boxes + imgQ * 4);
  float bm = -INFINITY;
  for (int i = tid; i < Q; i += 256) {
    float4 v = bp4[i];
    bm = fmaxf(bm, fmaxf(fmaxf(v.x, v.y), fmaxf(v.z, v.w)));
  }
  #pragma unroll
  for (int s = 32; s > 0; s >>= 1) bm = fmaxf(bm, __shfl_xor(bm, s));
  if (lane == 0) s_wmax[wid] = bm;
  __syncthreads();
  float bmax = fmaxf(fmaxf(s_wmax[0], s_wmax[1]), fmaxf(s_wmax[2], s_wmax[3]));

  // prefetch labels/scores (independent loads, pipelined), then ballot-compact
  int lb[15]; float sc[15];
  #pragma unroll
  for (int e = 0; e < 15; e++) {
    int i = e * 64 + lane;
    lb[e] = (i < Q) ? labels[imgQ + i] : -1;
    sc[e] = (i < Q) ? scores[imgQ + i] : 0.0f;
  }
  unsigned long long lmask = (1ull << lane) - 1ull;
  int n = 0;
  #pragma unroll
  for (int e = 0; e < 15; e++) {
    bool memb = (lb[e] == c);
    unsigned long long mm = __ballot(memb);
    if (memb) {
      int pos = n + __popcll(mm & lmask);
      if (pos < 64) { s_idx[wid][pos] = e * 64 + lane; s_sc[wid][pos] = sc[e]; }
    }
    n += __popcll(mm);
  }
  n = min(n, 64);
  __syncthreads();

  int   myidx = (lane < n) ? s_idx[wid][lane] : 0;
  float mysc  = (lane < n) ? s_sc[wid][lane]  : -INFINITY;

  // stable rank: (score desc, original index asc); gathered order is index-asc
  int rank = 0;
  for (int j = 0; j < n; j++) {
    float sj = __shfl(mysc, j);
    rank += (sj > mysc) || (sj == mysc && j < lane);
  }
  if (lane < n) { s_srt[wid][rank] = myidx; s_ssc[wid][rank] = mysc; }
  __syncthreads();
  int   oi = (lane < n) ? s_srt[wid][lane] : 0;   // lane = sorted position
  float os = (lane < n) ? s_ssc[wid][lane] : 0.0f;

  // offset box (replicates reference rounding: per-element +off)
  float b0 = 0.f, b1 = 0.f, b2 = 0.f, b3 = 0.f;
  if (lane < n) {
    float off = (float)c * (bmax + 1.0f);
    const float* bp = boxes + (imgQ + oi) * 4;
    b0 = bp[0] + off; b1 = bp[1] + off;
    b2 = bp[2] + off; b3 = bp[3] + off;
  }
  float areaA = (b2 - b0) * (b3 - b1);

  // suppression row: bits j > lane with iou > 0.5
  unsigned long long sup = 0;
  for (int j = 0; j < n; j++) {
    float c0 = __shfl(b0, j), c1 = __shfl(b1, j);
    float c2 = __shfl(b2, j), c3 = __shfl(b3, j);
    if (j > lane && lane < n) {
      float ltx = fmaxf(b0, c0), lty = fmaxf(b1, c1);
      float rbx = fminf(b2, c2), rby = fminf(b3, c3);
      float ww = fmaxf(rbx - ltx, 0.0f), hh = fmaxf(rby - lty, 0.0f);
      float inter = ww * hh;
      float areaB = (c2 - c0) * (c3 - c1);
      float uni = areaA + areaB - inter;
      float denom = (uni == 0.0f) ? 1.0f : uni;
      if (inter / denom > 0.5f) sup |= (1ull << j);
    }
  }

  // greedy sweep (dependent chain length n ~ 11)
  unsigned long long keepm = (n >= 64) ? ~0ull : ((1ull << n) - 1ull);
  for (int i = 0; i < n; i++) {
    unsigned long long row = __shfl(sup, i);
    if ((keepm >> i) & 1ull) keepm &= ~row;
  }

  if (lane < n) {
    int kept = (int)((keepm >> lane) & 1ull);
    hsc[imgQ + oi] = (kept && c == 0) ? os : NEGV;
    osc[imgQ + oi] = (kept && c != 0) ? os : NEGV;
  }
}

// ---------------- top-15: wave0 = humans (hsc), wave1 = objects (osc) ----------------
__global__ __launch_bounds__(128) void k_topk(const float* __restrict__ hsc,
                                              const float* __restrict__ osc,
                                              int* __restrict__ tki,
                                              float* __restrict__ tkf) {
  int img = blockIdx.x;
  int wid = threadIdx.x >> 6, lane = threadIdx.x & 63;
  const float* src = (wid == 0) ? hsc : osc;
  float v[15];
  int cnt = 0;
  #pragma unroll
  for (int e = 0; e < 15; e++) {
    int i = e * 64 + lane;
    float val = (i < Q) ? src[(size_t)img * Q + i] : -INFINITY;
    cnt += (val >= 0.2f) ? 1 : 0;
    v[e] = val;
  }
  #pragma unroll
  for (int s = 32; s > 0; s >>= 1) cnt += __shfl_xor(cnt, s);

  float selv = 0.f; int seli = 0;
  for (int r = 0; r < 15; r++) {
    float bv_ = -INFINITY; int bi_ = 0x7fffffff;
    #pragma unroll
    for (int e = 0; e < 15; e++) { if (v[e] > bv_) { bv_ = v[e]; bi_ = e * 64 + lane; } }
    #pragma unroll
    for (int s = 32; s > 0; s >>= 1) {
      float ov = __shfl_xor(bv_, s); int oi = __shfl_xor(bi_, s);
      if (ov > bv_ || (ov == bv_ && oi < bi_)) { bv_ = ov; bi_ = oi; }
    }
    if (lane == r) { selv = bv_; seli = bi_; }
    if ((bi_ & 63) == lane) {
      int ee = bi_ >> 6;
      #pragma unroll
      for (int e = 0; e < 15; e++) if (e == ee) v[e] = -2.0e9f;
    }
  }
  int kk = min(max(cnt, 3), 15);
  if (lane < 15) {
    tki[img * 96 + wid * 15 + lane]      = seli;
    tkf[img * 96 + 30 + wid * 15 + lane] = selv;
    tki[img * 96 + 60 + wid * 15 + lane] = (lane < kk && selv > -5.0e8f) ? 1 : 0;
  }
}

// ================= GEMM, grid (4 n-slices, 64 images), full K ==========
__global__ __launch_bounds__(256) void k_gemm2(const float* __restrict__ hs,
                                               const int* __restrict__ tki,
                                               const float* __restrict__ Wv,
                                               const float* __restrict__ Wb,
                                               float* __restrict__ Cm) {
  int ns = blockIdx.x, img = blockIdx.y, t = threadIdx.x;
  __shared__ float s_At[256][40];   // A transposed [k][row], row pitch 160B (16B-aligned)
  __shared__ float s_B[32][64];
  __shared__ int s_row[30];
  if (t < 30) s_row[t] = tki[img * 96 + t];
  __syncthreads();
  // stage A transposed: f = q*30 + r  (lanes hit distinct rows -> conflict-free LDS writes)
  for (int f = t; f < 1920; f += 256) {
    int r = f % 30, q = f / 30;     // q = float4 chunk 0..63
    float4 a = *(const float4*)(hs + ((size_t)img * Q + s_row[r]) * HD + q * 4);
    s_At[q * 4 + 0][r] = a.x;
    s_At[q * 4 + 1][r] = a.y;
    s_At[q * 4 + 2][r] = a.z;
    s_At[q * 4 + 3][r] = a.w;
  }
  // per-thread B column source (branch hoisted)
  int col = ns * 64 + (t & 63);
  const float* Wsrc = nullptr; int roff = 0, kadd = 0, wstride = 0;
  if (col < 117)      { Wsrc = Wv; roff = col;       kadd = 0;   wstride = 117; }
  else if (col < 125) { Wsrc = Wb; roff = col - 117; kadd = 0;   wstride = 8; }
  else if (col < 242) { Wsrc = Wv; roff = col - 125; kadd = 256; wstride = 117; }
  else if (col < 250) { Wsrc = Wb; roff = col - 242; kadd = 256; wstride = 8; }

  int a = t >> 6;                   // row group: rows 8a..8a+7
  float acc[8] = {0, 0, 0, 0, 0, 0, 0, 0};
  __syncthreads();
  for (int kc = 0; kc < 256; kc += 32) {
    #pragma unroll
    for (int pp = 0; pp < 8; pp++) {
      int k_l = (t >> 6) + pp * 4;
      s_B[k_l][t & 63] = Wsrc ? Wsrc[(size_t)(kc + k_l + kadd) * wstride + roff] : 0.0f;
    }
    __syncthreads();
    #pragma unroll
    for (int kk = 0; kk < 32; kk++) {
      float4 a0 = *(const float4*)(&s_At[kc + kk][8 * a]);       // broadcast reads
      float4 a1 = *(const float4*)(&s_At[kc + kk][8 * a + 4]);
      float b = s_B[kk][t & 63];
      acc[0] += a0.x * b; acc[1] += a0.y * b; acc[2] += a0.z * b; acc[3] += a0.w * b;
      acc[4] += a1.x * b; acc[5] += a1.y * b; acc[6] += a1.z * b; acc[7] += a1.w * b;
    }
    __syncthreads();
  }
  #pragma unroll
  for (int j = 0; j < 8; j++) {
    int r = 8 * a + j;
    if (r < 30) Cm[((size_t)img * 30 + r) * 256 + col] = acc[j];
  }
}

// ================= epilogue, all four outputs ==========
__global__ __launch_bounds__(512) void k_out2(const float* __restrict__ boxes,
                                              const float* __restrict__ sizes,
                                              const float* __restrict__ Cm,
                                              const int* __restrict__ tki,
                                              const float* __restrict__ tkf,
                                              const float* __restrict__ bverb,
                                              const float* __restrict__ bbox,
                                              float* __restrict__ out) {
  int img = blockIdx.x, t = threadIdx.x;
  __shared__ float s_C[30 * 256];
  __shared__ float s_pr[225];
  __shared__ int s_ih[15], s_io[15];
  const float4* base = (const float4*)(Cm + (size_t)img * 7680);
  for (int e = t; e < 1920; e += 512) ((float4*)s_C)[e] = base[e];
  if (t < 15) { s_ih[t] = tki[img * 96 + t]; s_io[t] = tki[img * 96 + 15 + t]; }
  if (t < 225) {
    int h_ = t / 15, o_ = t - h_ * 15;
    float th = tkf[img * 96 + 30 + h_], to_ = tkf[img * 96 + 45 + o_];
    int vh = tki[img * 96 + 60 + h_], vo = tki[img * 96 + 75 + o_];
    s_pr[t] = (vh && vo) ? th * to_ : 0.0f;
  }
  __syncthreads();

  float hgt = sizes[img * 2 + 0], wid = sizes[img * 2 + 1];
  float* out0 = out;
  float* out1 = out + 7680;
  float* out2 = out + 65280;
  float* out3 = out + 122880;

  if (t < 30) {
    int q = (t < 15) ? s_ih[t] : s_io[t - 15];
    const float* bp = boxes + ((size_t)img * Q + q) * 4;
    float cx = bp[0], cy = bp[1], w = bp[2], h = bp[3];
    float* o = out0 + ((size_t)img * 30 + t) * 4;
    o[0] = (cx - 0.5f * w) * wid;
    o[1] = (cy - 0.5f * h) * hgt;
    o[2] = (cx + 0.5f * w) * wid;
    o[3] = (cy + 0.5f * h) * hgt;
  }

  if (t < 225) {
    int h_ = t / 15, o_ = t - h_ * 15;
    {
      float d0 = s_C[h_ * 256 + 117] + s_C[(15 + o_) * 256 + 242] + bbox[0];
      float d1 = s_C[h_ * 256 + 118] + s_C[(15 + o_) * 256 + 243] + bbox[1];
      float d2 = s_C[h_ * 256 + 119] + s_C[(15 + o_) * 256 + 244] + bbox[2];
      float d3 = s_C[h_ * 256 + 120] + s_C[(15 + o_) * 256 + 245] + bbox[3];
      int q = s_ih[h_];
      const float* bp = boxes + ((size_t)img * Q + q) * 4;
      float cx = bp[0], cy = bp[1], w = bp[2], h = bp[3];
      float cx2 = cx + d0 * w, cy2 = cy + d1 * h;
      float w2 = w * expf(d2), h2 = h * expf(d3);
      float* o = out1 + ((size_t)img * 225 + t) * 4;
      o[0] = (cx2 - 0.5f * w2) * wid;
      o[1] = (cy2 - 0.5f * h2) * hgt;
      o[2] = (cx2 + 0.5f * w2) * wid;
      o[3] = (cy2 + 0.5f * h2) * hgt;
    }
    {
      float d4 = s_C[h_ * 256 + 121] + s_C[(15 + o_) * 256 + 246] + bbox[4];
      float d5 = s_C[h_ * 256 + 122] + s_C[(15 + o_) * 256 + 247] + bbox[5];
      float d6 = s_C[h_ * 256 + 123] + s_C[(15 + o_) * 256 + 248] + bbox[6];
      float d7 = s_C[h_ * 256 + 124] + s_C[(15 + o_) * 256 + 249] + bbox[7];
      int q = s_io[o_];
      const float* bp = boxes + ((size_t)img * Q + q) * 4;
      float cx = bp[0], cy = bp[1], w = bp[2], h = bp[3];
      float cx2 = cx + d4 * w, cy2 = cy + d5 * h;
      float w2 = w * expf(d6), h2 = h * expf(d7);
      float* o = out2 + ((size_t)img * 225 + t) * 4;
      o[0] = (cx2 - 0.5f * w2) * wid;
      o[1] = (cy2 - 0.5f * h2) * hgt;
      o[2] = (cx2 + 0.5f * w2) * wid;
      o[3] = (cy2 + 0.5f * h2) * hgt;
    }
  }

  for (int e = t; e < 225 * 117; e += 512) {
    int p = e / 117, v = e - p * 117;
    int ph = p / 15, po = p - ph * 15;
    float x = s_C[ph * 256 + v] + s_C[(15 + po) * 256 + 125 + v] + bverb[v];
    out3[(size_t)img * 26325 + e] = (1.0f / (1.0f + expf(-x))) * s_pr[p];
  }
}

extern "C" void kernel_launch(void* const* d_in, const int* in_sizes, int n_in,
                              void* d_out, int out_size, void* d_ws, size_t ws_size,
                              hipStream_t stream) {
  const float* logits = (const float*)d_in[0];
  const float* boxes  = (const float*)d_in[1];
  const float* hs     = (const float*)d_in[2];
  const float* sizes  = (const float*)d_in[3];
  const float* Wv     = (const float*)d_in[4];
  const float* bv     = (const float*)d_in[5];
  const float* Wb     = (const float*)d_in[6];
  const float* bb     = (const float*)d_in[7];
  float* out = (float*)d_out;
  char* ws = (char*)d_ws;

  float* scores = (float*)(ws + OFF_SCORES);
  int*   labels = (int*)(ws + OFF_LABELS);
  float* hsc    = (float*)(ws + OFF_HSC);
  float* osc    = (float*)(ws + OFF_OSC);
  int*   tki    = (int*)(ws + OFF_TK);
  float* tkf    = (float*)(ws + OFF_TK);
  float* Cm     = (float*)(ws + OFF_CM);

  k_score<<<900, 256, 0, stream>>>(logits, scores, labels);
  k_cnms<<<dim3(NB, 20), 256, 0, stream>>>(scores, labels, boxes, hsc, osc);
  k_topk<<<NB, 128, 0, stream>>>(hsc, osc, tki, tkf);
  k_gemm2<<<dim3(4, NB), 256, 0, stream>>>(hs, tki, Wv, Wb, Cm);
  k_out2<<<NB, 512, 0, stream>>>(boxes, sizes, Cm, tki, tkf, bv, bb, out);
}